// Round 1
// baseline (392.785 us; speedup 1.0000x reference)
//
#include <hip/hip_runtime.h>
#include <hip/hip_bf16.h>

typedef __attribute__((ext_vector_type(8))) short bf16x8;
typedef __attribute__((ext_vector_type(4))) float f32x4;

#define NB 2048      // batch
#define ND 1280      // per-stream dim
#define NK 5120      // 4*ND
#define NE 512       // EMBED

static __device__ inline unsigned short f2bf(float x) {
    union { float f; unsigned u; } c; c.f = x;
    unsigned r = c.u + 0x7FFFu + ((c.u >> 16) & 1u);
    return (unsigned short)(r >> 16);
}

// ---------------------------------------------------------------------------
// Kernel 1: fused masked-mean over T for all 4 segments -> feat bf16 [B][4D]
// grid: 4 segs * 2048 b * 320 float4-chunks / 256 = 10240 blocks
// ---------------------------------------------------------------------------
__global__ __launch_bounds__(256) void reduce_kernel(
    const float4* __restrict__ q, const float4* __restrict__ vq,
    const float4* __restrict__ aa, const float4* __restrict__ va,
    const int* __restrict__ qlen, const int* __restrict__ alen,
    ushort4* __restrict__ feat)
{
    const int tid = blockIdx.x * 256 + threadIdx.x;
    const int per_seg = NB * (ND / 4);          // 655360
    const int seg = tid / per_seg;              // uniform per block
    const int r = tid - seg * per_seg;
    const int b = r / (ND / 4);
    const int ch = r - b * (ND / 4);

    const float4* src;
    int len;
    if (seg == 0)      { src = q;  len = qlen[b]; }
    else if (seg == 1) { src = vq; len = 64; }
    else if (seg == 2) { src = aa; len = alen[b]; }
    else               { src = va; len = 64; }

    const long base = (long)b * (ND / 4) + ch;
    const long stride = (long)NB * (ND / 4);    // one t-plane in float4s

    float4 acc = make_float4(0.f, 0.f, 0.f, 0.f);
    #pragma unroll 4
    for (int t = 0; t < len; ++t) {
        float4 v = src[base + (long)t * stride];
        acc.x += v.x; acc.y += v.y; acc.z += v.z; acc.w += v.w;
    }
    const float inv = 1.0f / (float)len;
    ushort4 o;
    o.x = f2bf(acc.x * inv);
    o.y = f2bf(acc.y * inv);
    o.z = f2bf(acc.z * inv);
    o.w = f2bf(acc.w * inv);
    feat[(long)b * (NK / 4) + seg * (ND / 4) + ch] = o;
}

// ---------------------------------------------------------------------------
// Kernel 2: W1 [5120][512] f32 -> W1T [512][5120] bf16 (transpose + convert)
// grid: (5120/32) * (512/32) = 160*16 = 2560 blocks, 256 threads
// ---------------------------------------------------------------------------
__global__ __launch_bounds__(256) void w1t_kernel(
    const float* __restrict__ W1, unsigned short* __restrict__ w1t)
{
    __shared__ unsigned short lds[32][33];
    const int bid = blockIdx.x;
    const int kb = (bid >> 4) * 32;
    const int nb = (bid & 15) * 32;
    const int tx = threadIdx.x & 31;
    const int ty = threadIdx.x >> 5;   // 0..7
    #pragma unroll
    for (int i = 0; i < 4; ++i) {
        int k = kb + ty + i * 8;
        lds[ty + i * 8][tx] = f2bf(W1[(long)k * NE + nb + tx]);
    }
    __syncthreads();
    #pragma unroll
    for (int i = 0; i < 4; ++i) {
        int n = nb + ty + i * 8;
        w1t[(long)n * NK + kb + tx] = lds[tx][ty + i * 8];
    }
}

// ---------------------------------------------------------------------------
// Kernel 3: bf16 MFMA GEMM  h_part[s] = feat[:, ks] @ W1T[:, ks]^T
// tiles 64x64, split-K=4, grid = 256 tiles * 4 = 1024 blocks, 256 threads
// ---------------------------------------------------------------------------
__global__ __launch_bounds__(256) void gemm_kernel(
    const unsigned short* __restrict__ feat, const unsigned short* __restrict__ w1t,
    float* __restrict__ hpart)
{
    __shared__ int4 As[64 * 9];   // 64 rows * 144B (pad 16B) -> 2-way max aliasing
    __shared__ int4 Bs[64 * 9];

    const int bid = blockIdx.x;
    const int tile = bid & 255;
    const int s = bid >> 8;                 // K-slice 0..3
    const int m0 = (tile >> 3) << 6;        // 0..1984
    const int n0 = (tile & 7) << 6;         // 0..448
    const int kbeg = s * (NK / 4);          // 1280 per slice

    const int t = threadIdx.x;
    const int l = t & 63;
    const int w = t >> 6;
    const int wm = (w >> 1) * 32;
    const int wn = (w & 1) * 32;
    const int srow = t >> 3;                // 0..31
    const int scol = t & 7;                 // 16B chunk in k

    f32x4 acc[2][2] = {};

    for (int k0 = kbeg; k0 < kbeg + NK / 4; k0 += 64) {
        const unsigned short* Ag = feat + (long)(m0 + srow) * NK + k0 + scol * 8;
        const unsigned short* Bg = w1t + (long)(n0 + srow) * NK + k0 + scol * 8;
        int4 a0 = *(const int4*)Ag;
        int4 a1 = *(const int4*)(Ag + 32L * NK);
        int4 b0 = *(const int4*)Bg;
        int4 b1v = *(const int4*)(Bg + 32L * NK);
        As[srow * 9 + scol] = a0;
        As[(srow + 32) * 9 + scol] = a1;
        Bs[srow * 9 + scol] = b0;
        Bs[(srow + 32) * 9 + scol] = b1v;
        __syncthreads();
        #pragma unroll
        for (int kk = 0; kk < 2; ++kk) {
            const int kc = kk * 4 + (l >> 4);   // 16B chunk index within row
            bf16x8 af0 = *(const bf16x8*)&As[(wm + (l & 15)) * 9 + kc];
            bf16x8 af1 = *(const bf16x8*)&As[(wm + 16 + (l & 15)) * 9 + kc];
            bf16x8 bf0 = *(const bf16x8*)&Bs[(wn + (l & 15)) * 9 + kc];
            bf16x8 bf1 = *(const bf16x8*)&Bs[(wn + 16 + (l & 15)) * 9 + kc];
            acc[0][0] = __builtin_amdgcn_mfma_f32_16x16x32_bf16(af0, bf0, acc[0][0], 0, 0, 0);
            acc[0][1] = __builtin_amdgcn_mfma_f32_16x16x32_bf16(af0, bf1, acc[0][1], 0, 0, 0);
            acc[1][0] = __builtin_amdgcn_mfma_f32_16x16x32_bf16(af1, bf0, acc[1][0], 0, 0, 0);
            acc[1][1] = __builtin_amdgcn_mfma_f32_16x16x32_bf16(af1, bf1, acc[1][1], 0, 0, 0);
        }
        __syncthreads();
    }

    float* hp = hpart + (long)s * NB * NE;
    const int rbase = m0 + wm + ((l >> 4) << 2);
    const int cbase = n0 + wn + (l & 15);
    #pragma unroll
    for (int mi = 0; mi < 2; ++mi)
        #pragma unroll
        for (int ni = 0; ni < 2; ++ni)
            #pragma unroll
            for (int rr = 0; rr < 4; ++rr)
                hp[(long)(rbase + mi * 16 + rr) * NE + cbase + ni * 16] = acc[mi][ni][rr];
}

// ---------------------------------------------------------------------------
// Kernel 4: combine split-K partials + bias + ELU -> h; per-block col partials
// grid: 64 blocks * 256 threads; block handles 32 rows; thread owns 2 cols
// ---------------------------------------------------------------------------
__global__ __launch_bounds__(256) void combine_kernel(
    const float* __restrict__ hpart, const float* __restrict__ b1,
    float* __restrict__ h, float* __restrict__ part1, float* __restrict__ part2)
{
    const int blk = blockIdx.x;
    const int t = threadIdx.x;
    const int c = t * 2;
    const float bx = b1[c], by = b1[c + 1];
    float s1x = 0.f, s1y = 0.f, s2x = 0.f, s2y = 0.f;
    const float2* hp = (const float2*)hpart;
    float2* h2 = (float2*)h;
    const long SL = (long)NB * NE / 2;
    for (int i = 0; i < 32; ++i) {
        long row = (long)blk * 32 + i;
        long idx = row * (NE / 2) + t;
        float2 v0 = hp[idx];
        float2 v1 = hp[idx + SL];
        float2 v2 = hp[idx + 2 * SL];
        float2 v3 = hp[idx + 3 * SL];
        float hx = v0.x + v1.x + v2.x + v3.x + bx;
        float hy = v0.y + v1.y + v2.y + v3.y + by;
        hx = hx > 0.f ? hx : expm1f(hx);
        hy = hy > 0.f ? hy : expm1f(hy);
        h2[idx] = make_float2(hx, hy);
        s1x += hx; s2x += hx * hx;
        s1y += hy; s2y += hy * hy;
    }
    float2* p1 = (float2*)part1;
    float2* p2 = (float2*)part2;
    p1[blk * (NE / 2) + t] = make_float2(s1x, s1y);
    p2[blk * (NE / 2) + t] = make_float2(s2x, s2y);
}

// ---------------------------------------------------------------------------
// Kernel 5: BN stats -> fold BN * gamma + beta and W2 into coefA[e] and cst
// out[b] = sum_e h[b][e] * coefA[e] + cst
// ---------------------------------------------------------------------------
__global__ __launch_bounds__(512) void finalize_kernel(
    const float* __restrict__ part1, const float* __restrict__ part2,
    const float* __restrict__ gamma, const float* __restrict__ beta,
    const float* __restrict__ W2, const float* __restrict__ b2,
    float* __restrict__ coefA, float* __restrict__ cst)
{
    const int e = threadIdx.x;
    float s1 = 0.f, s2 = 0.f;
    for (int i = 0; i < 64; ++i) {
        s1 += part1[i * NE + e];
        s2 += part2[i * NE + e];
    }
    const float mu = s1 * (1.0f / NB);
    const float var = s2 * (1.0f / NB) - mu * mu;
    const float rs = rsqrtf(var + 1e-5f);
    const float g = gamma[e], w = W2[e];
    coefA[e] = rs * g * w;
    float term = (beta[e] - mu * rs * g) * w;
    __shared__ float red[512];
    red[e] = term;
    __syncthreads();
    for (int off = 256; off > 0; off >>= 1) {
        if (e < off) red[e] += red[e + off];
        __syncthreads();
    }
    if (e == 0) cst[0] = red[0] + b2[0];
}

// ---------------------------------------------------------------------------
// Kernel 6: out[b] = dot(h[b,:], coefA) + cst   (one wave per row)
// grid: 512 blocks * 256 threads (4 waves)
// ---------------------------------------------------------------------------
__global__ __launch_bounds__(256) void out_kernel(
    const float* __restrict__ h, const float* __restrict__ coefA,
    const float* __restrict__ cst, float* __restrict__ out)
{
    const int w = threadIdx.x >> 6;
    const int l = threadIdx.x & 63;
    const int row = blockIdx.x * 4 + w;
    const float4* h4 = (const float4*)(h + (long)row * NE);
    const float4* c4 = (const float4*)coefA;
    float4 x0 = h4[l * 2], x1 = h4[l * 2 + 1];
    float4 c0 = c4[l * 2], c1 = c4[l * 2 + 1];
    float dot = x0.x * c0.x + x0.y * c0.y + x0.z * c0.z + x0.w * c0.w
              + x1.x * c1.x + x1.y * c1.y + x1.z * c1.z + x1.w * c1.w;
    #pragma unroll
    for (int off = 32; off > 0; off >>= 1) dot += __shfl_down(dot, off);
    if (l == 0) out[row] = dot + cst[0];
}

// ---------------------------------------------------------------------------
extern "C" void kernel_launch(void* const* d_in, const int* in_sizes, int n_in,
                              void* d_out, int out_size, void* d_ws, size_t ws_size,
                              hipStream_t stream)
{
    const float* q    = (const float*)d_in[0];
    const float* vq   = (const float*)d_in[1];
    const float* aa   = (const float*)d_in[2];
    const float* va   = (const float*)d_in[3];
    const float* W1   = (const float*)d_in[4];
    const float* b1   = (const float*)d_in[5];
    const float* gam  = (const float*)d_in[6];
    const float* bet  = (const float*)d_in[7];
    const float* W2   = (const float*)d_in[8];
    const float* b2   = (const float*)d_in[9];
    const int* qlen   = (const int*)d_in[10];
    const int* alen   = (const int*)d_in[11];
    float* out = (float*)d_out;

    char* ws = (char*)d_ws;
    unsigned short* feat = (unsigned short*)ws;                 // 20,971,520 B
    unsigned short* w1t  = (unsigned short*)(ws + 20971520);    //  5,242,880 B
    float* hbuf          = (float*)(ws + 26214400);             //  4,194,304 B
    float* hpart         = (float*)(ws + 30408704);             // 16,777,216 B
    float* part1         = (float*)(ws + 47185920);             //    131,072 B
    float* part2         = (float*)(ws + 47316992);             //    131,072 B
    float* coefA         = (float*)(ws + 47448064);             //      2,048 B
    float* cst           = (float*)(ws + 47450112);             //          4 B

    reduce_kernel<<<10240, 256, 0, stream>>>(
        (const float4*)q, (const float4*)vq, (const float4*)aa, (const float4*)va,
        qlen, alen, (ushort4*)feat);

    w1t_kernel<<<2560, 256, 0, stream>>>(W1, w1t);

    gemm_kernel<<<1024, 256, 0, stream>>>(feat, w1t, hpart);

    combine_kernel<<<64, 256, 0, stream>>>(hpart, b1, hbuf, part1, part2);

    finalize_kernel<<<1, 512, 0, stream>>>(part1, part2, gam, bet, W2, b2, coefA, cst);

    out_kernel<<<512, 256, 0, stream>>>(hbuf, coefA, cst, out);
}